// Round 13
// baseline (207.465 us; speedup 1.0000x reference)
//
#include <hip/hip_runtime.h>
#include <hip/hip_bf16.h>
#include <stdint.h>

#define S_LEN 4096
#define D_MODEL 1024
#define N_HEADS 16
#define D_HEAD 64
#define LDQKV 3072
#define SCALE_LOG2E 0.1803368787f   // (1/sqrt(64)) * log2(e)

typedef __attribute__((ext_vector_type(4))) float f32x4;
typedef __attribute__((ext_vector_type(16))) float f32x16;
typedef __attribute__((ext_vector_type(8))) __bf16 bf16x8;
typedef __attribute__((ext_vector_type(4))) __bf16 bf16x4;

__device__ __forceinline__ unsigned short f2bf(float f) {
    union { float f; unsigned u; } x{f};
    unsigned r = x.u + 0x7fff + ((x.u >> 16) & 1);
    return (unsigned short)(r >> 16);
}

__device__ __forceinline__ unsigned pk2(float a, float b) {
    union { __bf16 h; unsigned short u; } ua{(__bf16)a}, ub{(__bf16)b};
    return (unsigned)ua.u | ((unsigned)ub.u << 16);
}

__device__ __forceinline__ void gld_lds16(const void* g, void* l) {
    __builtin_amdgcn_global_load_lds(
        (const __attribute__((address_space(1))) unsigned int*)g,
        (__attribute__((address_space(3))) unsigned int*)l, 16, 0, 0);
}

// ---------------- fused prep: x->bf16, weights->bf16, RoPE tables ----------------
__global__ __launch_bounds__(256) void prep_k(const float* __restrict__ x,
                                              const float* __restrict__ Wq,
                                              const float* __restrict__ Wk,
                                              const float* __restrict__ Wv,
                                              const float* __restrict__ Wo,
                                              const int* __restrict__ pos,
                                              unsigned short* __restrict__ xb,
                                              unsigned short* __restrict__ Wb,
                                              float* __restrict__ ct,
                                              float* __restrict__ st) {
    int b = blockIdx.x;
    if (b < 4096) {
        int i = (b * 256 + threadIdx.x) * 4;
        float4 v = *(const float4*)&x[i];
        ushort4 o;
        o.x = f2bf(v.x); o.y = f2bf(v.y); o.z = f2bf(v.z); o.w = f2bf(v.w);
        *(ushort4*)&xb[i] = o;
    } else if (b < 8192) {
        int i = ((b - 4096) * 256 + threadIdx.x) * 4;   // over 4 x 1M
        int sel = i >> 20;
        int off = i & ((1 << 20) - 1);
        const float* src = (sel == 0) ? Wq : (sel == 1) ? Wk : (sel == 2) ? Wv : Wo;
        float4 v = *(const float4*)&src[off];
        ushort4 o;
        o.x = f2bf(v.x); o.y = f2bf(v.y); o.z = f2bf(v.z); o.w = f2bf(v.w);
        *(ushort4*)&Wb[i] = o;
    } else {
        // extended table [4096][64]: k<32 real RoPE, k>=32 identity (for V cols)
        int i = (b - 8192) * 256 + threadIdx.x;   // [0, 4096*64)
        int s = i >> 6, k = i & 63;
        if (k < 32) {
            float invf = __builtin_exp2f(-(float)(2 * k) * (1.0f / 64.0f) * 13.287712379549449f);
            float ang = (float)pos[s] * invf;
            ct[i] = cosf(ang);
            st[i] = sinf(ang);
        } else {
            ct[i] = 1.0f;
            st[i] = 0.0f;
        }
    }
}

// ---------------- V transpose: QKV V-cols [S][3072 (+2048)] -> Vt [1024][S] ----------------
__global__ __launch_bounds__(256) void vtrans_k(const unsigned short* __restrict__ src,
                                                unsigned short* __restrict__ dst) {
    __shared__ unsigned short tile[64 * 68];
    const int bs = blockIdx.x * 64;   // s tile
    const int bd = blockIdx.y * 64;   // d tile
    const int t = threadIdx.x;
    {
        int col = (t & 7) * 8;
        #pragma unroll
        for (int rr = 0; rr < 2; ++rr) {
            int row = rr * 32 + (t >> 3);
            const unsigned short* g = src + (size_t)(bs + row) * LDQKV + bd + col;
            ushort4 a = *(const ushort4*)g;
            ushort4 b = *(const ushort4*)(g + 4);
            *(ushort4*)&tile[row * 68 + col] = a;
            *(ushort4*)&tile[row * 68 + col + 4] = b;
        }
    }
    __syncthreads();
    {
        int dl = t >> 2;             // 0..63 d row
        int sc = (t & 3) * 16;       // s chunk
        ushort4 o[4];
        #pragma unroll
        for (int e = 0; e < 16; ++e)
            ((unsigned short*)o)[e] = tile[(sc + e) * 68 + dl];
        unsigned short* g = dst + (size_t)(bd + dl) * S_LEN + bs + sc;
        *(ushort4*)(g + 0)  = o[0];
        *(ushort4*)(g + 4)  = o[1];
        *(ushort4*)(g + 8)  = o[2];
        *(ushort4*)(g + 12) = o[3];
    }
}

// ---------------- fused QKV GEMM: C[S][3072] = x * [Wq;Wk;Wv]^T ----------------
__global__ __launch_bounds__(256) void gemm_qkv_k(const unsigned short* __restrict__ A,
                                                  const unsigned short* __restrict__ B,
                                                  unsigned short* __restrict__ C,
                                                  const float* __restrict__ ct,
                                                  const float* __restrict__ st) {
    __shared__ unsigned short lA[128 * 64];
    __shared__ unsigned short lB[128 * 64];
    const int t = threadIdx.x, w = t >> 6, l = t & 63;
    const int tm = blockIdx.y * 128, tn = blockIdx.x * 128;
    const int wm = (w >> 1) * 64, wn = (w & 1) * 64;
    const int g = l >> 4, ln = l & 15;

    f32x4 acc[4][4] = {};

    for (int k0 = 0; k0 < 1024; k0 += 64) {
        #pragma unroll
        for (int r = 0; r < 4; ++r) {
            int row = 8 * (4 * r + w) + (l >> 3);
            gld_lds16(A + (size_t)(tm + row) * 1024 + k0 + (l & 7) * 8, &lA[(4 * r + w) * 512]);
            gld_lds16(B + (size_t)(tn + row) * 1024 + k0 + (l & 7) * 8, &lB[(4 * r + w) * 512]);
        }
        asm volatile("s_waitcnt vmcnt(0)" ::: "memory");
        __syncthreads();

        #pragma unroll
        for (int kk = 0; kk < 2; ++kk) {
            bf16x8 af[4], bf[4];
            #pragma unroll
            for (int i = 0; i < 4; ++i) {
                af[i] = *(const bf16x8*)&lA[(wm + i * 16 + ln) * 64 + kk * 32 + g * 8];
                bf[i] = *(const bf16x8*)&lB[(wn + i * 16 + ln) * 64 + kk * 32 + g * 8];
            }
            #pragma unroll
            for (int i = 0; i < 4; ++i)
                #pragma unroll
                for (int j = 0; j < 4; ++j)
                    acc[i][j] = __builtin_amdgcn_mfma_f32_16x16x32_bf16(af[i], bf[j], acc[i][j], 0, 0, 0);
        }
        __syncthreads();
    }

    // epilogue: RoPE (identity for V) + Q pre-scale, all lanes same path
    #pragma unroll
    for (int i = 0; i < 4; ++i) {
        #pragma unroll
        for (int j = 0; j < 4; ++j) {
            int col = tn + wn + j * 16 + ln;
            int dd = col & 63;
            int tb = ((col >= 2048) ? 32 : 0) + (dd >> 1);
            float scl = (col < 1024) ? SCALE_LOG2E : 1.0f;
            #pragma unroll
            for (int r = 0; r < 4; ++r) {
                int row = tm + wm + i * 16 + g * 4 + r;
                float v = acc[i][j][r];
                float p = __shfl_xor(v, 1, 64);
                float c = ct[row * 64 + tb];
                float s = st[row * 64 + tb];
                v = ((dd & 1) ? (s * p + c * v) : (c * v - s * p)) * scl;
                C[(size_t)row * LDQKV + col] = f2bf(v);
            }
        }
    }
}

// ---------------- out GEMM: out[S][1024] f32 = ctx * Wo^T, 64x128 tiles ----------------
__global__ __launch_bounds__(256) void gemm_o_k(const unsigned short* __restrict__ A,
                                                const unsigned short* __restrict__ B,
                                                float* __restrict__ C) {
    __shared__ unsigned short lA[64 * 64];    // 8 KB
    __shared__ unsigned short lB[128 * 64];   // 16 KB
    const int t = threadIdx.x, w = t >> 6, l = t & 63;
    const int tm = blockIdx.y * 64, tn = blockIdx.x * 128;
    const int wm = (w >> 1) * 32, wn = (w & 1) * 64;
    const int g = l >> 4, ln = l & 15;

    f32x4 acc[2][4] = {};

    for (int k0 = 0; k0 < 1024; k0 += 64) {
        #pragma unroll
        for (int r = 0; r < 2; ++r) {
            int row = r * 32 + w * 8 + (l >> 3);
            gld_lds16(A + (size_t)(tm + row) * 1024 + k0 + (l & 7) * 8, &lA[(r * 32 + w * 8) * 64]);
        }
        #pragma unroll
        for (int r = 0; r < 4; ++r) {
            int row = 8 * (4 * r + w) + (l >> 3);
            gld_lds16(B + (size_t)(tn + row) * 1024 + k0 + (l & 7) * 8, &lB[(4 * r + w) * 512]);
        }
        asm volatile("s_waitcnt vmcnt(0)" ::: "memory");
        __syncthreads();

        #pragma unroll
        for (int kk = 0; kk < 2; ++kk) {
            bf16x8 af[2], bf[4];
            #pragma unroll
            for (int i = 0; i < 2; ++i)
                af[i] = *(const bf16x8*)&lA[(wm + i * 16 + ln) * 64 + kk * 32 + g * 8];
            #pragma unroll
            for (int j = 0; j < 4; ++j)
                bf[j] = *(const bf16x8*)&lB[(wn + j * 16 + ln) * 64 + kk * 32 + g * 8];
            #pragma unroll
            for (int i = 0; i < 2; ++i)
                #pragma unroll
                for (int j = 0; j < 4; ++j)
                    acc[i][j] = __builtin_amdgcn_mfma_f32_16x16x32_bf16(af[i], bf[j], acc[i][j], 0, 0, 0);
        }
        __syncthreads();
    }

    #pragma unroll
    for (int i = 0; i < 2; ++i)
        #pragma unroll
        for (int j = 0; j < 4; ++j) {
            int col = tn + wn + j * 16 + ln;
            #pragma unroll
            for (int r = 0; r < 4; ++r) {
                int row = tm + wm + i * 16 + g * 4 + r;
                C[(size_t)row * 1024 + col] = acc[i][j][r];
            }
        }
}

// ---------------- causal flash attention: 32x32 MFMA, in-register P ----------
// block: 256 thr = 4 waves; waves 0-1 -> q-tile qA, waves 2-3 -> qB=63-qA.
// Wave owns 32 q-rows. Swapped S^T = K Q^T with mfma_32x32x16; the C-layout
// (col=lane&31=q, row=(reg&3)+8(reg>>2)+4(lane>>5)=k) makes softmax per-lane
// (1 shfl_xor(32) to partner) and P^T fragments buildable in registers
// (cvt-pack + shfl_xor(32)), deleting the P LDS roundtrip.
__device__ __forceinline__ void stage4(const unsigned short* __restrict__ Kb,
                                       const unsigned short* __restrict__ Vt,
                                       unsigned short* lK, unsigned short* lV,
                                       int h, int kt, int w, int l) {
    const int chunk = (l & 7) ^ (l >> 3);   // source pre-swizzle (row&7 == l>>3)
    #pragma unroll
    for (int r2 = 0; r2 < 2; ++r2) {
        int row = r2 * 32 + w * 8 + (l >> 3);
        gld_lds16(Kb + (size_t)(kt * 64 + row) * LDQKV + h * 64 + chunk * 8,
                  lK + r2 * 2048 + w * 512);
        gld_lds16(Vt + (size_t)(h * 64 + row) * S_LEN + kt * 64 + chunk * 8,
                  lV + r2 * 2048 + w * 512);
    }
}

__global__ __launch_bounds__(256) void attn_k(const unsigned short* __restrict__ Qb,
                                              const unsigned short* __restrict__ Kb,
                                              const unsigned short* __restrict__ Vt,
                                              unsigned short* __restrict__ ctxb) {
    __shared__ unsigned short lK[2][64 * 64];   // K tile [k][d], swizzled (reused in epilogue)
    __shared__ unsigned short lV[2][64 * 64];   // V^T tile [d][k], swizzled

    const int t = threadIdx.x, w = t >> 6, l = t & 63;
    const int h = blockIdx.x;
    const int qA = blockIdx.y;              // 0..31
    const int qB = 63 - qA;                 // 32..63
    const int qT = (w < 2) ? qA : qB;
    const int q0w = qT * 64 + (w & 1) * 32;
    const int lq = l & 31;                  // q within wave tile
    const int hi = l >> 5;                  // lane half
    const int q = q0w + lq;

    // persistent Q row: d = s*16 + hi*8 + (0..7), 4 x bf16x8 (B-operand)
    bf16x8 aq[4];
    #pragma unroll
    for (int s = 0; s < 4; ++s)
        aq[s] = *(const bf16x8*)&Qb[(size_t)q * LDQKV + h * 64 + s * 16 + hi * 8];

    f32x16 acc0 = {}, acc1 = {};            // ctx^T d-tiles 0-31 / 32-63
    float rm = -INFINITY, rs = 0.0f;

    stage4(Kb, Vt, &lK[0][0], &lV[0][0], h, 0, w, l);
    asm volatile("s_waitcnt vmcnt(0)" ::: "memory");
    __syncthreads();

    int cur = 0;
    for (int kt = 0; kt <= qB; ++kt) {
        if (kt < qB)
            stage4(Kb, Vt, &lK[cur ^ 1][0], &lV[cur ^ 1][0], h, kt + 1, w, l);

        if (kt <= qT) {   // wave-uniform guard
            const char* lKc = (const char*)&lK[cur][0];
            const char* lVc = (const char*)&lV[cur][0];

            // ---- S^T = K Q^T : z0 = k-rows 0-31, z1 = 32-63 ----
            f32x16 z0 = {}, z1 = {};
            __builtin_amdgcn_s_setprio(1);
            #pragma unroll
            for (int s = 0; s < 4; ++s) {
                int r0 = lq, r1 = 32 + lq;
                int off0 = (r0 * 128 + s * 32 + hi * 16) ^ ((r0 & 7) << 4);
                int off1 = (r1 * 128 + s * 32 + hi * 16) ^ ((r1 & 7) << 4);
                bf16x8 k0 = *(const bf16x8*)(lKc + off0);
                bf16x8 k1 = *(const bf16x8*)(lKc + off1);
                z0 = __builtin_amdgcn_mfma_f32_32x32x16_bf16(k0, aq[s], z0, 0, 0, 0);
                z1 = __builtin_amdgcn_mfma_f32_32x32x16_bf16(k1, aq[s], z1, 0, 0, 0);
            }
            __builtin_amdgcn_s_setprio(0);

            // ---- causal mask (diagonal tile only) ----
            if (kt == qT) {
                #pragma unroll
                for (int r = 0; r < 16; ++r) {
                    int kg = kt * 64 + (r & 3) + 8 * (r >> 2) + 4 * hi;
                    if (kg > q)      z0[r] = -INFINITY;
                    if (kg + 32 > q) z1[r] = -INFINITY;
                }
            }

            // ---- online softmax (exp2 domain, defer-max THR=8) ----
            float mx = fmaxf(z0[0], z1[0]);
            #pragma unroll
            for (int r = 1; r < 16; ++r) mx = fmaxf(mx, fmaxf(z0[r], z1[r]));
            mx = fmaxf(mx, __shfl_xor(mx, 32, 64));   // partner holds other 32 k of same q
            if (__any(mx > rm + 8.0f)) {
                float mn = fmaxf(rm, mx);
                float fac = __builtin_amdgcn_exp2f(rm - mn);
                rm = mn;
                rs *= fac;
                #pragma unroll
                for (int r = 0; r < 16; ++r) { acc0[r] *= fac; acc1[r] *= fac; }
            }
            float ps = 0.0f;
            #pragma unroll
            for (int r = 0; r < 16; ++r) {
                z0[r] = __builtin_amdgcn_exp2f(z0[r] - rm); ps += z0[r];
                z1[r] = __builtin_amdgcn_exp2f(z1[r] - rm); ps += z1[r];
            }
            ps += __shfl_xor(ps, 32, 64);
            rs += ps;

            // ---- build P^T B-fragments in registers ----
            // k(m,r,hi) = m*32 + (r&3)+8*(r>>2) + 4*hi; step s needs k = s*16+hi*8+j.
            // Static blocks: s0:z0[0..7], s1:z0[8..15], s2:z1[0..7], s3:z1[8..15];
            // lower 4 (A) from hi=0 lanes, upper 4 (B) from hi=1 lanes -> one swap each.
            bf16x8 bp[4];
            #pragma unroll
            for (int s = 0; s < 4; ++s) {
                float e0, e1, e2, e3, f0, f1, f2, f3;
                if (s == 0) { e0=z0[0]; e1=z0[1]; e2=z0[2]; e3=z0[3]; f0=z0[4]; f1=z0[5]; f2=z0[6]; f3=z0[7]; }
                else if (s == 1) { e0=z0[8]; e1=z0[9]; e2=z0[10]; e3=z0[11]; f0=z0[12]; f1=z0[13]; f2=z0[14]; f3=z0[15]; }
                else if (s == 2) { e0=z1[0]; e1=z1[1]; e2=z1[2]; e3=z1[3]; f0=z1[4]; f1=z1[5]; f2=z1[6]; f3=z1[7]; }
                else             { e0=z1[8]; e1=z1[9]; e2=z1[10]; e3=z1[11]; f0=z1[12]; f1=z1[13]; f2=z1[14]; f3=z1[15]; }
                unsigned A0 = pk2(e0, e1), A1 = pk2(e2, e3);
                unsigned B0 = pk2(f0, f1), B1 = pk2(f2, f3);
                unsigned RA0 = (unsigned)__shfl_xor((int)A0, 32, 64);
                unsigned RA1 = (unsigned)__shfl_xor((int)A1, 32, 64);
                unsigned RB0 = (unsigned)__shfl_xor((int)B0, 32, 64);
                unsigned RB1 = (unsigned)__shfl_xor((int)B1, 32, 64);
                union { uint4 u; bf16x8 v; } cv;
                cv.u.x = hi ? RB0 : A0;
                cv.u.y = hi ? RB1 : A1;
                cv.u.z = hi ? B0  : RA0;
                cv.u.w = hi ? B1  : RA1;
                bp[s] = cv.v;
            }

            // ---- ctx^T += V^T P^T ----
            __builtin_amdgcn_s_setprio(1);
            #pragma unroll
            for (int s = 0; s < 4; ++s) {
                int r0 = lq, r1 = 32 + lq;
                int off0 = (r0 * 128 + s * 32 + hi * 16) ^ ((r0 & 7) << 4);
                int off1 = (r1 * 128 + s * 32 + hi * 16) ^ ((r1 & 7) << 4);
                bf16x8 v0 = *(const bf16x8*)(lVc + off0);
                bf16x8 v1 = *(const bf16x8*)(lVc + off1);
                acc0 = __builtin_amdgcn_mfma_f32_32x32x16_bf16(v0, bp[s], acc0, 0, 0, 0);
                acc1 = __builtin_amdgcn_mfma_f32_32x32x16_bf16(v1, bp[s], acc1, 0, 0, 0);
            }
            __builtin_amdgcn_s_setprio(0);
        }

        asm volatile("s_waitcnt vmcnt(0)" ::: "memory");
        __syncthreads();
        cur ^= 1;
    }

    // ---- epilogue: transpose via wave-private LDS region, coalesced store ----
    unsigned short* lw = &lK[0][0] + w * 2048;   // 32q x 64d bf16 = 4 KB per wave
    float inv = 1.0f / rs;
    #pragma unroll
    for (int r = 0; r < 16; ++r) {
        int d0 = (r & 3) + 8 * (r >> 2) + 4 * hi;
        lw[lq * 64 + d0]      = f2bf(acc0[r] * inv);
        lw[lq * 64 + 32 + d0] = f2bf(acc1[r] * inv);
    }
    // wave-private write->read: compiler-ordered lgkmcnt (same array)
    {
        int qloc = l >> 1, half = l & 1;
        const unsigned short* src = lw + qloc * 64 + half * 32;
        unsigned short* gdst = ctxb + (size_t)(q0w + qloc) * D_MODEL + h * 64 + half * 32;
        #pragma unroll
        for (int c = 0; c < 4; ++c)
            *(uint4*)(gdst + c * 8) = *(const uint4*)(src + c * 8);
    }
}

// ---------------- host side ----------------
extern "C" void kernel_launch(void* const* d_in, const int* in_sizes, int n_in,
                              void* d_out, int out_size, void* d_ws, size_t ws_size,
                              hipStream_t stream) {
    const float* x  = (const float*)d_in[0];
    const float* Wq = (const float*)d_in[1];
    const float* Wk = (const float*)d_in[2];
    const float* Wv = (const float*)d_in[3];
    const float* Wo = (const float*)d_in[4];
    const int* tpos = (const int*)d_in[5];
    float* out = (float*)d_out;

    char* ws = (char*)d_ws;
    unsigned short* xb   = (unsigned short*)(ws + 0);            // 8 MB (dead after QKV gemm)
    unsigned short* Wb   = (unsigned short*)(ws + (8u << 20));   // 8 MB (Wq,Wk,Wv,Wo bf16)
    unsigned short* QKV  = (unsigned short*)(ws + (16u << 20));  // 24 MB [S][3072]
    unsigned short* ctxb = (unsigned short*)(ws + (40u << 20));  // 8 MB
    float* costab = (float*)(ws + (48u << 20));                  // 1 MB [4096][64]
    float* sintab = (float*)(ws + (49u << 20));                  // 1 MB
    unsigned short* Vtb  = xb;   // reuse: written by vtrans after QKV gemm

    // prep: x->bf16 | weights->bf16 | extended RoPE tables
    prep_k<<<9216, 256, 0, stream>>>(x, Wq, Wk, Wv, Wo, tpos, xb, Wb, costab, sintab);

    // fused QKV projection with RoPE/scale epilogue: 768 blocks = 3/CU
    gemm_qkv_k<<<dim3(24, 32), 256, 0, stream>>>(xb, Wb, QKV, costab, sintab);

    // V transpose: QKV cols 2048.. -> Vt [1024][S]
    vtrans_k<<<dim3(S_LEN / 64, D_MODEL / 64), 256, 0, stream>>>(QKV + 2048, Vtb);

    // paired causal attention (32x32 MFMA, in-register P): 512 blocks x 256 thr
    attn_k<<<dim3(N_HEADS, 32), 256, 0, stream>>>(QKV, QKV + 1024, Vtb, ctxb);

    // out projection, 64x128 tiles: 512 blocks = 2/CU
    gemm_o_k<<<dim3(8, 64), 256, 0, stream>>>(ctxb, Wb + 3u * 1024 * 1024, out);
}

// Round 14
// 176.281 us; speedup vs baseline: 1.1769x; 1.1769x over previous
//
#include <hip/hip_runtime.h>
#include <hip/hip_bf16.h>
#include <stdint.h>

#define S_LEN 4096
#define D_MODEL 1024
#define N_HEADS 16
#define D_HEAD 64
#define LDQKV 3072
#define SCALE_LOG2E 0.1803368787f   // (1/sqrt(64)) * log2(e)

typedef __attribute__((ext_vector_type(4))) float f32x4;
typedef __attribute__((ext_vector_type(8))) __bf16 bf16x8;
typedef __attribute__((ext_vector_type(4))) __bf16 bf16x4;

__device__ __forceinline__ unsigned short f2bf(float f) {
    union { float f; unsigned u; } x{f};
    unsigned r = x.u + 0x7fff + ((x.u >> 16) & 1);
    return (unsigned short)(r >> 16);
}

__device__ __forceinline__ void gld_lds16(const void* g, void* l) {
    __builtin_amdgcn_global_load_lds(
        (const __attribute__((address_space(1))) unsigned int*)g,
        (__attribute__((address_space(3))) unsigned int*)l, 16, 0, 0);
}

// ---------------- fused prep: x->bf16, weights->bf16, RoPE tables ----------------
__global__ __launch_bounds__(256) void prep_k(const float* __restrict__ x,
                                              const float* __restrict__ Wq,
                                              const float* __restrict__ Wk,
                                              const float* __restrict__ Wv,
                                              const float* __restrict__ Wo,
                                              const int* __restrict__ pos,
                                              unsigned short* __restrict__ xb,
                                              unsigned short* __restrict__ Wb,
                                              float* __restrict__ ct,
                                              float* __restrict__ st) {
    int b = blockIdx.x;
    if (b < 4096) {
        int i = (b * 256 + threadIdx.x) * 4;
        float4 v = *(const float4*)&x[i];
        ushort4 o;
        o.x = f2bf(v.x); o.y = f2bf(v.y); o.z = f2bf(v.z); o.w = f2bf(v.w);
        *(ushort4*)&xb[i] = o;
    } else if (b < 8192) {
        int i = ((b - 4096) * 256 + threadIdx.x) * 4;   // over 4 x 1M
        int sel = i >> 20;
        int off = i & ((1 << 20) - 1);
        const float* src = (sel == 0) ? Wq : (sel == 1) ? Wk : (sel == 2) ? Wv : Wo;
        float4 v = *(const float4*)&src[off];
        ushort4 o;
        o.x = f2bf(v.x); o.y = f2bf(v.y); o.z = f2bf(v.z); o.w = f2bf(v.w);
        *(ushort4*)&Wb[i] = o;
    } else {
        // extended table [4096][64]: k<32 real RoPE, k>=32 identity (for V cols)
        int i = (b - 8192) * 256 + threadIdx.x;   // [0, 4096*64)
        int s = i >> 6, k = i & 63;
        if (k < 32) {
            float invf = __builtin_exp2f(-(float)(2 * k) * (1.0f / 64.0f) * 13.287712379549449f);
            float ang = (float)pos[s] * invf;
            ct[i] = cosf(ang);
            st[i] = sinf(ang);
        } else {
            ct[i] = 1.0f;
            st[i] = 0.0f;
        }
    }
}

// ---------------- V transpose: QKV V-cols [S][3072 (+2048)] -> Vt [1024][S] ----------------
__global__ __launch_bounds__(256) void vtrans_k(const unsigned short* __restrict__ src,
                                                unsigned short* __restrict__ dst) {
    __shared__ unsigned short tile[64 * 68];
    const int bs = blockIdx.x * 64;   // s tile
    const int bd = blockIdx.y * 64;   // d tile
    const int t = threadIdx.x;
    {
        int col = (t & 7) * 8;
        #pragma unroll
        for (int rr = 0; rr < 2; ++rr) {
            int row = rr * 32 + (t >> 3);
            const unsigned short* g = src + (size_t)(bs + row) * LDQKV + bd + col;
            ushort4 a = *(const ushort4*)g;
            ushort4 b = *(const ushort4*)(g + 4);
            *(ushort4*)&tile[row * 68 + col] = a;
            *(ushort4*)&tile[row * 68 + col + 4] = b;
        }
    }
    __syncthreads();
    {
        int dl = t >> 2;             // 0..63 d row
        int sc = (t & 3) * 16;       // s chunk
        ushort4 o[4];
        #pragma unroll
        for (int e = 0; e < 16; ++e)
            ((unsigned short*)o)[e] = tile[(sc + e) * 68 + dl];
        unsigned short* g = dst + (size_t)(bd + dl) * S_LEN + bs + sc;
        *(ushort4*)(g + 0)  = o[0];
        *(ushort4*)(g + 4)  = o[1];
        *(ushort4*)(g + 8)  = o[2];
        *(ushort4*)(g + 12) = o[3];
    }
}

// ---------------- fused QKV GEMM: C[S][3072] = x * [Wq;Wk;Wv]^T ----------------
__global__ __launch_bounds__(256) void gemm_qkv_k(const unsigned short* __restrict__ A,
                                                  const unsigned short* __restrict__ B,
                                                  unsigned short* __restrict__ C,
                                                  const float* __restrict__ ct,
                                                  const float* __restrict__ st) {
    __shared__ unsigned short lA[128 * 64];
    __shared__ unsigned short lB[128 * 64];
    const int t = threadIdx.x, w = t >> 6, l = t & 63;
    const int tm = blockIdx.y * 128, tn = blockIdx.x * 128;
    const int wm = (w >> 1) * 64, wn = (w & 1) * 64;
    const int g = l >> 4, ln = l & 15;

    f32x4 acc[4][4] = {};

    for (int k0 = 0; k0 < 1024; k0 += 64) {
        #pragma unroll
        for (int r = 0; r < 4; ++r) {
            int row = 8 * (4 * r + w) + (l >> 3);
            gld_lds16(A + (size_t)(tm + row) * 1024 + k0 + (l & 7) * 8, &lA[(4 * r + w) * 512]);
            gld_lds16(B + (size_t)(tn + row) * 1024 + k0 + (l & 7) * 8, &lB[(4 * r + w) * 512]);
        }
        asm volatile("s_waitcnt vmcnt(0)" ::: "memory");
        __syncthreads();

        #pragma unroll
        for (int kk = 0; kk < 2; ++kk) {
            bf16x8 af[4], bf[4];
            #pragma unroll
            for (int i = 0; i < 4; ++i) {
                af[i] = *(const bf16x8*)&lA[(wm + i * 16 + ln) * 64 + kk * 32 + g * 8];
                bf[i] = *(const bf16x8*)&lB[(wn + i * 16 + ln) * 64 + kk * 32 + g * 8];
            }
            #pragma unroll
            for (int i = 0; i < 4; ++i)
                #pragma unroll
                for (int j = 0; j < 4; ++j)
                    acc[i][j] = __builtin_amdgcn_mfma_f32_16x16x32_bf16(af[i], bf[j], acc[i][j], 0, 0, 0);
        }
        __syncthreads();
    }

    // epilogue: RoPE (identity for V) + Q pre-scale, all lanes same path
    #pragma unroll
    for (int i = 0; i < 4; ++i) {
        #pragma unroll
        for (int j = 0; j < 4; ++j) {
            int col = tn + wn + j * 16 + ln;
            int dd = col & 63;
            int tb = ((col >= 2048) ? 32 : 0) + (dd >> 1);
            float scl = (col < 1024) ? SCALE_LOG2E : 1.0f;
            #pragma unroll
            for (int r = 0; r < 4; ++r) {
                int row = tm + wm + i * 16 + g * 4 + r;
                float v = acc[i][j][r];
                float p = __shfl_xor(v, 1, 64);
                float c = ct[row * 64 + tb];
                float s = st[row * 64 + tb];
                v = ((dd & 1) ? (s * p + c * v) : (c * v - s * p)) * scl;
                C[(size_t)row * LDQKV + col] = f2bf(v);
            }
        }
    }
}

// ---------------- out GEMM: out[S][1024] f32 = ctx * Wo^T, 64x128 tiles ----------------
__global__ __launch_bounds__(256) void gemm_o_k(const unsigned short* __restrict__ A,
                                                const unsigned short* __restrict__ B,
                                                float* __restrict__ C) {
    __shared__ unsigned short lA[64 * 64];    // 8 KB
    __shared__ unsigned short lB[128 * 64];   // 16 KB
    const int t = threadIdx.x, w = t >> 6, l = t & 63;
    const int tm = blockIdx.y * 64, tn = blockIdx.x * 128;
    const int wm = (w >> 1) * 32, wn = (w & 1) * 64;
    const int g = l >> 4, ln = l & 15;

    f32x4 acc[2][4] = {};

    for (int k0 = 0; k0 < 1024; k0 += 64) {
        #pragma unroll
        for (int r = 0; r < 2; ++r) {
            int row = r * 32 + w * 8 + (l >> 3);
            gld_lds16(A + (size_t)(tm + row) * 1024 + k0 + (l & 7) * 8, &lA[(r * 32 + w * 8) * 64]);
        }
        #pragma unroll
        for (int r = 0; r < 4; ++r) {
            int row = 8 * (4 * r + w) + (l >> 3);
            gld_lds16(B + (size_t)(tn + row) * 1024 + k0 + (l & 7) * 8, &lB[(4 * r + w) * 512]);
        }
        asm volatile("s_waitcnt vmcnt(0)" ::: "memory");
        __syncthreads();

        #pragma unroll
        for (int kk = 0; kk < 2; ++kk) {
            bf16x8 af[2], bf[4];
            #pragma unroll
            for (int i = 0; i < 2; ++i)
                af[i] = *(const bf16x8*)&lA[(wm + i * 16 + ln) * 64 + kk * 32 + g * 8];
            #pragma unroll
            for (int j = 0; j < 4; ++j)
                bf[j] = *(const bf16x8*)&lB[(wn + j * 16 + ln) * 64 + kk * 32 + g * 8];
            #pragma unroll
            for (int i = 0; i < 2; ++i)
                #pragma unroll
                for (int j = 0; j < 4; ++j)
                    acc[i][j] = __builtin_amdgcn_mfma_f32_16x16x32_bf16(af[i], bf[j], acc[i][j], 0, 0, 0);
        }
        __syncthreads();
    }

    #pragma unroll
    for (int i = 0; i < 2; ++i)
        #pragma unroll
        for (int j = 0; j < 4; ++j) {
            int col = tn + wn + j * 16 + ln;
            #pragma unroll
            for (int r = 0; r < 4; ++r) {
                int row = tm + wm + i * 16 + g * 4 + r;
                C[(size_t)row * 1024 + col] = acc[i][j][r];
            }
        }
}

// ---------------- causal flash attention: 32-row q-tiles, paired, 4-wave blocks ----
// q-tiles of 32 rows (128 per head); pair (qA, 127-qA) -> uniform 65 tile-units.
// grid (16 heads, 64 pairs) = 1024 blocks x 256 thr = 4 waves -> 4 blocks/CU
// (LDS 40KB), 4 independent barrier domains per CU (vs R11's 2).
// Inner code identical to the proven R11 kernel.
__device__ __forceinline__ void stage4(const unsigned short* __restrict__ Kb,
                                       const unsigned short* __restrict__ Vt,
                                       unsigned short* lK, unsigned short* lV,
                                       int h, int kt, int w, int l) {
    const int half = w & 1;
    const int chunk = (l & 7) ^ (l >> 3);   // source pre-swizzle (row&7 == l>>3)
    if (w < 2) {
        #pragma unroll
        for (int r2 = 0; r2 < 4; ++r2) {
            int row = half * 32 + r2 * 8 + (l >> 3);
            gld_lds16(Kb + (size_t)(kt * 64 + row) * LDQKV + h * 64 + chunk * 8,
                      lK + half * 2048 + r2 * 512);
        }
    } else {
        #pragma unroll
        for (int r2 = 0; r2 < 4; ++r2) {
            int row = half * 32 + r2 * 8 + (l >> 3);
            gld_lds16(Vt + (size_t)(h * 64 + row) * S_LEN + kt * 64 + chunk * 8,
                      lV + half * 2048 + r2 * 512);
        }
    }
}

__global__ __launch_bounds__(256) void attn_k(const unsigned short* __restrict__ Qb,
                                              const unsigned short* __restrict__ Kb,
                                              const unsigned short* __restrict__ Vt,
                                              unsigned short* __restrict__ ctxb) {
    __shared__ unsigned short lK[2][64 * 64];   // K tile [k][d], swizzled   16 KB
    __shared__ unsigned short lV[2][64 * 64];   // V^T tile [d][k], swizzled 16 KB
    __shared__ unsigned short lP[4][16 * 64];   // per-wave P [q][k]          8 KB

    const int t = threadIdx.x, w = t >> 6, l = t & 63;
    const int wv = w & 1;                   // 16-row half within 32-row tile
    const int sel = w >> 1;                 // 0 -> qA, 1 -> qB
    const int h = blockIdx.x;
    const int qA = blockIdx.y;              // 0..63 (32-row tile index)
    const int qB = 127 - qA;                // 64..127
    const int qT = sel ? qB : qA;
    const int q0 = qT * 32 + wv * 16;
    const int ktT = qT >> 1;                // this wave's diagonal kv-tile (64-wide)
    const int ktB = qB >> 1;                // block loop bound
    const int g = l >> 4, ln = l & 15;

    // Q fragments (B-operand for swapped QK^T; pre-scaled by scale*log2e)
    bf16x8 aq[2];
    #pragma unroll
    for (int kk = 0; kk < 2; ++kk)
        aq[kk] = *(const bf16x8*)&Qb[(size_t)(q0 + ln) * LDQKV + h * 64 + kk * 32 + g * 8];

    f32x4 acc[4] = {};
    float rm = -INFINITY, rs = 0.0f;
    char* lpw = (char*)&lP[w][0];

    stage4(Kb, Vt, &lK[0][0], &lV[0][0], h, 0, w, l);
    asm volatile("s_waitcnt vmcnt(0)" ::: "memory");
    __syncthreads();

    int cur = 0;
    for (int kt = 0; kt <= ktB; ++kt) {
        if (kt < ktB)
            stage4(Kb, Vt, &lK[cur ^ 1][0], &lV[cur ^ 1][0], h, kt + 1, w, l);

        if (kt <= ktT) {   // wave-uniform: this wave's q-tile still has kv left
            // ---- S^T = K Q^T  (lane: q = ln; k = ct*16 + g*4 + r) ----
            float p[16];
            __builtin_amdgcn_s_setprio(1);
            #pragma unroll
            for (int ct = 0; ct < 4; ++ct) {
                f32x4 z = {};
                #pragma unroll
                for (int kk = 0; kk < 2; ++kk) {
                    int row = ct * 16 + ln;
                    int off = (row * 128 + kk * 64 + g * 16) ^ ((row & 7) << 4);
                    bf16x8 ak = *(const bf16x8*)((const char*)&lK[cur][0] + off);
                    z = __builtin_amdgcn_mfma_f32_16x16x32_bf16(ak, aq[kk], z, 0, 0, 0);
                }
                #pragma unroll
                for (int r = 0; r < 4; ++r) p[ct * 4 + r] = z[r];
            }
            __builtin_amdgcn_s_setprio(0);

            // ---- causal mask (diagonal tile only; general kg>q test) ----
            if (kt == ktT) {
                int qg = q0 + ln;
                #pragma unroll
                for (int ct = 0; ct < 4; ++ct)
                    #pragma unroll
                    for (int r = 0; r < 4; ++r)
                        if (kt * 64 + ct * 16 + g * 4 + r > qg) p[ct * 4 + r] = -INFINITY;
            }

            // ---- online softmax, exp2 domain, defer-max (THR=8) ----
            float pmax = fmaxf(p[0], p[1]);
            #pragma unroll
            for (int i = 2; i < 16; i += 2)
                pmax = fmaxf(fmaxf(pmax, p[i]), p[i + 1]);
            pmax = fmaxf(pmax, __shfl_xor(pmax, 16, 64));
            pmax = fmaxf(pmax, __shfl_xor(pmax, 32, 64));
            if (__any(pmax > rm + 8.0f)) {
                float mn = fmaxf(rm, pmax);
                float fac = __builtin_amdgcn_exp2f(rm - mn);
                rm = mn;
                rs *= fac;
                #pragma unroll
                for (int mb = 0; mb < 4; ++mb) {
                    f32x4 a = acc[mb];
                    #pragma unroll
                    for (int r = 0; r < 4; ++r) a[r] *= fac;
                    acc[mb] = a;
                }
            }
            float ps = 0.0f;
            #pragma unroll
            for (int i = 0; i < 16; ++i) {
                float e = __builtin_amdgcn_exp2f(p[i] - rm);   // bounded by 2^8
                p[i] = e;
                ps += e;
            }
            ps += __shfl_xor(ps, 16, 64);
            ps += __shfl_xor(ps, 32, 64);
            rs += ps;

            // ---- pack P (bf16) to wave-private LDS (compiler-ordered) ----
            #pragma unroll
            for (int ct = 0; ct < 4; ++ct) {
                bf16x4 pv;
                pv[0] = (__bf16)p[ct * 4 + 0];
                pv[1] = (__bf16)p[ct * 4 + 1];
                pv[2] = (__bf16)p[ct * 4 + 2];
                pv[3] = (__bf16)p[ct * 4 + 3];
                int off = (ln * 128 + ct * 32 + g * 8) ^ ((ln & 7) << 4);
                *(bf16x4*)(lpw + off) = pv;
            }

            // ---- ctx^T += V^T P^T  (lane: q = ln; d = mb*16 + g*4 + r) ----
            __builtin_amdgcn_s_setprio(1);
            #pragma unroll
            for (int mb = 0; mb < 4; ++mb) {
                #pragma unroll
                for (int kc = 0; kc < 2; ++kc) {
                    int vrow = mb * 16 + ln;
                    int voff = (vrow * 128 + kc * 64 + g * 16) ^ ((vrow & 7) << 4);
                    bf16x8 av = *(const bf16x8*)((const char*)&lV[cur][0] + voff);
                    int poff = (ln * 128 + kc * 64 + g * 16) ^ ((ln & 7) << 4);
                    bf16x8 bp = *(const bf16x8*)(lpw + poff);
                    acc[mb] = __builtin_amdgcn_mfma_f32_16x16x32_bf16(av, bp, acc[mb], 0, 0, 0);
                }
            }
            __builtin_amdgcn_s_setprio(0);
        }

        // end-of-tile: prefetch landed + all waves done with buffer cur
        asm volatile("s_waitcnt vmcnt(0)" ::: "memory");
        __syncthreads();
        cur ^= 1;
    }

    // ---- write ctx (bf16), vectorized 8B stores ----
    float inv = 1.0f / rs;
    #pragma unroll
    for (int mb = 0; mb < 4; ++mb) {
        bf16x4 o;
        #pragma unroll
        for (int r = 0; r < 4; ++r) o[r] = (__bf16)(acc[mb][r] * inv);
        *(bf16x4*)&ctxb[(size_t)(q0 + ln) * D_MODEL + h * 64 + mb * 16 + g * 4] = o;
    }
}

// ---------------- host side ----------------
extern "C" void kernel_launch(void* const* d_in, const int* in_sizes, int n_in,
                              void* d_out, int out_size, void* d_ws, size_t ws_size,
                              hipStream_t stream) {
    const float* x  = (const float*)d_in[0];
    const float* Wq = (const float*)d_in[1];
    const float* Wk = (const float*)d_in[2];
    const float* Wv = (const float*)d_in[3];
    const float* Wo = (const float*)d_in[4];
    const int* tpos = (const int*)d_in[5];
    float* out = (float*)d_out;

    char* ws = (char*)d_ws;
    unsigned short* xb   = (unsigned short*)(ws + 0);            // 8 MB (dead after QKV gemm)
    unsigned short* Wb   = (unsigned short*)(ws + (8u << 20));   // 8 MB (Wq,Wk,Wv,Wo bf16)
    unsigned short* QKV  = (unsigned short*)(ws + (16u << 20));  // 24 MB [S][3072]
    unsigned short* ctxb = (unsigned short*)(ws + (40u << 20));  // 8 MB
    float* costab = (float*)(ws + (48u << 20));                  // 1 MB [4096][64]
    float* sintab = (float*)(ws + (49u << 20));                  // 1 MB
    unsigned short* Vtb  = xb;   // reuse: written by vtrans after QKV gemm

    // prep: x->bf16 | weights->bf16 | extended RoPE tables
    prep_k<<<9216, 256, 0, stream>>>(x, Wq, Wk, Wv, Wo, tpos, xb, Wb, costab, sintab);

    // fused QKV projection with RoPE/scale epilogue: 768 blocks = 3/CU
    gemm_qkv_k<<<dim3(24, 32), 256, 0, stream>>>(xb, Wb, QKV, costab, sintab);

    // V transpose: QKV cols 2048.. -> Vt [1024][S]
    vtrans_k<<<dim3(S_LEN / 64, D_MODEL / 64), 256, 0, stream>>>(QKV + 2048, Vtb);

    // paired causal attention, 32-row q-tiles: 1024 blocks x 4 waves
    attn_k<<<dim3(N_HEADS, 64), 256, 0, stream>>>(QKV, QKV + 1024, Vtb, ctxb);

    // out projection, 64x128 tiles: 512 blocks = 2/CU
    gemm_o_k<<<dim3(8, 64), 256, 0, stream>>>(ctxb, Wb + 3u * 1024 * 1024, out);
}

// Round 15
// 165.150 us; speedup vs baseline: 1.2562x; 1.0674x over previous
//
#include <hip/hip_runtime.h>
#include <hip/hip_bf16.h>
#include <stdint.h>

#define S_LEN 4096
#define D_MODEL 1024
#define N_HEADS 16
#define D_HEAD 64
#define LDQKV 3072
#define SCALE_LOG2E 0.1803368787f   // (1/sqrt(64)) * log2(e)

typedef __attribute__((ext_vector_type(4))) float f32x4;
typedef __attribute__((ext_vector_type(8))) __bf16 bf16x8;
typedef __attribute__((ext_vector_type(4))) __bf16 bf16x4;

__device__ __forceinline__ unsigned short f2bf(float f) {
    union { float f; unsigned u; } x{f};
    unsigned r = x.u + 0x7fff + ((x.u >> 16) & 1);
    return (unsigned short)(r >> 16);
}

__device__ __forceinline__ void gld_lds16(const void* g, void* l) {
    __builtin_amdgcn_global_load_lds(
        (const __attribute__((address_space(1))) unsigned int*)g,
        (__attribute__((address_space(3))) unsigned int*)l, 16, 0, 0);
}

// ---------------- fused prep: x->bf16, weights->bf16, RoPE tables ----------------
__global__ __launch_bounds__(256) void prep_k(const float* __restrict__ x,
                                              const float* __restrict__ Wq,
                                              const float* __restrict__ Wk,
                                              const float* __restrict__ Wv,
                                              const float* __restrict__ Wo,
                                              const int* __restrict__ pos,
                                              unsigned short* __restrict__ xb,
                                              unsigned short* __restrict__ Wb,
                                              float* __restrict__ ct,
                                              float* __restrict__ st) {
    int b = blockIdx.x;
    if (b < 4096) {
        int i = (b * 256 + threadIdx.x) * 4;
        float4 v = *(const float4*)&x[i];
        ushort4 o;
        o.x = f2bf(v.x); o.y = f2bf(v.y); o.z = f2bf(v.z); o.w = f2bf(v.w);
        *(ushort4*)&xb[i] = o;
    } else if (b < 8192) {
        int i = ((b - 4096) * 256 + threadIdx.x) * 4;   // over 4 x 1M
        int sel = i >> 20;
        int off = i & ((1 << 20) - 1);
        const float* src = (sel == 0) ? Wq : (sel == 1) ? Wk : (sel == 2) ? Wv : Wo;
        float4 v = *(const float4*)&src[off];
        ushort4 o;
        o.x = f2bf(v.x); o.y = f2bf(v.y); o.z = f2bf(v.z); o.w = f2bf(v.w);
        *(ushort4*)&Wb[i] = o;
    } else {
        // extended table [4096][64]: k<32 real RoPE, k>=32 identity (for V cols)
        int i = (b - 8192) * 256 + threadIdx.x;   // [0, 4096*64)
        int s = i >> 6, k = i & 63;
        if (k < 32) {
            float invf = __builtin_exp2f(-(float)(2 * k) * (1.0f / 64.0f) * 13.287712379549449f);
            float ang = (float)pos[s] * invf;
            ct[i] = cosf(ang);
            st[i] = sinf(ang);
        } else {
            ct[i] = 1.0f;
            st[i] = 0.0f;
        }
    }
}

// ---------------- V transpose: QKV V-cols [S][3072 (+2048)] -> Vt [1024][S] ----------------
__global__ __launch_bounds__(256) void vtrans_k(const unsigned short* __restrict__ src,
                                                unsigned short* __restrict__ dst) {
    __shared__ unsigned short tile[64 * 68];
    const int bs = blockIdx.x * 64;   // s tile
    const int bd = blockIdx.y * 64;   // d tile
    const int t = threadIdx.x;
    {
        int col = (t & 7) * 8;
        #pragma unroll
        for (int rr = 0; rr < 2; ++rr) {
            int row = rr * 32 + (t >> 3);
            const unsigned short* g = src + (size_t)(bs + row) * LDQKV + bd + col;
            ushort4 a = *(const ushort4*)g;
            ushort4 b = *(const ushort4*)(g + 4);
            *(ushort4*)&tile[row * 68 + col] = a;
            *(ushort4*)&tile[row * 68 + col + 4] = b;
        }
    }
    __syncthreads();
    {
        int dl = t >> 2;             // 0..63 d row
        int sc = (t & 3) * 16;       // s chunk
        ushort4 o[4];
        #pragma unroll
        for (int e = 0; e < 16; ++e)
            ((unsigned short*)o)[e] = tile[(sc + e) * 68 + dl];
        unsigned short* g = dst + (size_t)(bd + dl) * S_LEN + bs + sc;
        *(ushort4*)(g + 0)  = o[0];
        *(ushort4*)(g + 4)  = o[1];
        *(ushort4*)(g + 8)  = o[2];
        *(ushort4*)(g + 12) = o[3];
    }
}

// ---------------- fused QKV GEMM: C[S][3072] = x * [Wq;Wk;Wv]^T ----------------
__global__ __launch_bounds__(256) void gemm_qkv_k(const unsigned short* __restrict__ A,
                                                  const unsigned short* __restrict__ B,
                                                  unsigned short* __restrict__ C,
                                                  const float* __restrict__ ct,
                                                  const float* __restrict__ st) {
    __shared__ unsigned short lA[128 * 64];
    __shared__ unsigned short lB[128 * 64];
    const int t = threadIdx.x, w = t >> 6, l = t & 63;
    const int tm = blockIdx.y * 128, tn = blockIdx.x * 128;
    const int wm = (w >> 1) * 64, wn = (w & 1) * 64;
    const int g = l >> 4, ln = l & 15;

    f32x4 acc[4][4] = {};

    for (int k0 = 0; k0 < 1024; k0 += 64) {
        #pragma unroll
        for (int r = 0; r < 4; ++r) {
            int row = 8 * (4 * r + w) + (l >> 3);
            gld_lds16(A + (size_t)(tm + row) * 1024 + k0 + (l & 7) * 8, &lA[(4 * r + w) * 512]);
            gld_lds16(B + (size_t)(tn + row) * 1024 + k0 + (l & 7) * 8, &lB[(4 * r + w) * 512]);
        }
        asm volatile("s_waitcnt vmcnt(0)" ::: "memory");
        __syncthreads();

        #pragma unroll
        for (int kk = 0; kk < 2; ++kk) {
            bf16x8 af[4], bf[4];
            #pragma unroll
            for (int i = 0; i < 4; ++i) {
                af[i] = *(const bf16x8*)&lA[(wm + i * 16 + ln) * 64 + kk * 32 + g * 8];
                bf[i] = *(const bf16x8*)&lB[(wn + i * 16 + ln) * 64 + kk * 32 + g * 8];
            }
            #pragma unroll
            for (int i = 0; i < 4; ++i)
                #pragma unroll
                for (int j = 0; j < 4; ++j)
                    acc[i][j] = __builtin_amdgcn_mfma_f32_16x16x32_bf16(af[i], bf[j], acc[i][j], 0, 0, 0);
        }
        __syncthreads();
    }

    // epilogue: RoPE (identity for V) + Q pre-scale, all lanes same path
    #pragma unroll
    for (int i = 0; i < 4; ++i) {
        #pragma unroll
        for (int j = 0; j < 4; ++j) {
            int col = tn + wn + j * 16 + ln;
            int dd = col & 63;
            int tb = ((col >= 2048) ? 32 : 0) + (dd >> 1);
            float scl = (col < 1024) ? SCALE_LOG2E : 1.0f;
            #pragma unroll
            for (int r = 0; r < 4; ++r) {
                int row = tm + wm + i * 16 + g * 4 + r;
                float v = acc[i][j][r];
                float p = __shfl_xor(v, 1, 64);
                float c = ct[row * 64 + tb];
                float s = st[row * 64 + tb];
                v = ((dd & 1) ? (s * p + c * v) : (c * v - s * p)) * scl;
                C[(size_t)row * LDQKV + col] = f2bf(v);
            }
        }
    }
}

// ---------------- out GEMM: out[S][1024] f32 = ctx * Wo^T, 64x128 tiles ----------------
__global__ __launch_bounds__(256) void gemm_o_k(const unsigned short* __restrict__ A,
                                                const unsigned short* __restrict__ B,
                                                float* __restrict__ C) {
    __shared__ unsigned short lA[64 * 64];    // 8 KB
    __shared__ unsigned short lB[128 * 64];   // 16 KB
    const int t = threadIdx.x, w = t >> 6, l = t & 63;
    const int tm = blockIdx.y * 64, tn = blockIdx.x * 128;
    const int wm = (w >> 1) * 32, wn = (w & 1) * 64;
    const int g = l >> 4, ln = l & 15;

    f32x4 acc[2][4] = {};

    for (int k0 = 0; k0 < 1024; k0 += 64) {
        #pragma unroll
        for (int r = 0; r < 2; ++r) {
            int row = r * 32 + w * 8 + (l >> 3);
            gld_lds16(A + (size_t)(tm + row) * 1024 + k0 + (l & 7) * 8, &lA[(r * 32 + w * 8) * 64]);
        }
        #pragma unroll
        for (int r = 0; r < 4; ++r) {
            int row = 8 * (4 * r + w) + (l >> 3);
            gld_lds16(B + (size_t)(tn + row) * 1024 + k0 + (l & 7) * 8, &lB[(4 * r + w) * 512]);
        }
        asm volatile("s_waitcnt vmcnt(0)" ::: "memory");
        __syncthreads();

        #pragma unroll
        for (int kk = 0; kk < 2; ++kk) {
            bf16x8 af[2], bf[4];
            #pragma unroll
            for (int i = 0; i < 2; ++i)
                af[i] = *(const bf16x8*)&lA[(wm + i * 16 + ln) * 64 + kk * 32 + g * 8];
            #pragma unroll
            for (int j = 0; j < 4; ++j)
                bf[j] = *(const bf16x8*)&lB[(wn + j * 16 + ln) * 64 + kk * 32 + g * 8];
            #pragma unroll
            for (int i = 0; i < 2; ++i)
                #pragma unroll
                for (int j = 0; j < 4; ++j)
                    acc[i][j] = __builtin_amdgcn_mfma_f32_16x16x32_bf16(af[i], bf[j], acc[i][j], 0, 0, 0);
        }
        __syncthreads();
    }

    #pragma unroll
    for (int i = 0; i < 2; ++i)
        #pragma unroll
        for (int j = 0; j < 4; ++j) {
            int col = tn + wn + j * 16 + ln;
            #pragma unroll
            for (int r = 0; r < 4; ++r) {
                int row = tm + wm + i * 16 + g * 4 + r;
                C[(size_t)row * 1024 + col] = acc[i][j][r];
            }
        }
}

// ---------------- causal flash attention, PAIRED q-tiles for load balance ----
// grid: (16 heads, 32 pairs). block: 512 thr = 8 waves. Waves 0-3 own q-tile
// qA=blockIdx.y, waves 4-7 own qB=63-qA -> every block computes exactly 65
// kv-tile passes (uniform). Both tiles share the staged K/V for kt<=qA.
// ONE barrier per kv-tile; P buffer is wave-private (compiler-ordered).
__device__ __forceinline__ void stage8(const unsigned short* __restrict__ Kb,
                                       const unsigned short* __restrict__ Vt,
                                       unsigned short* lK, unsigned short* lV,
                                       int h, int kt, int w, int l) {
    const int half = w & 3;
    const int chunk = (l & 7) ^ (l >> 3);   // source pre-swizzle (row&7 == l>>3)
    if (w < 4) {
        #pragma unroll
        for (int r2 = 0; r2 < 2; ++r2) {
            int row = half * 16 + r2 * 8 + (l >> 3);
            gld_lds16(Kb + (size_t)(kt * 64 + row) * LDQKV + h * 64 + chunk * 8,
                      lK + half * 1024 + r2 * 512);
        }
    } else {
        #pragma unroll
        for (int r2 = 0; r2 < 2; ++r2) {
            int row = half * 16 + r2 * 8 + (l >> 3);
            gld_lds16(Vt + (size_t)(h * 64 + row) * S_LEN + kt * 64 + chunk * 8,
                      lV + half * 1024 + r2 * 512);
        }
    }
}

__global__ __launch_bounds__(512) void attn_k(const unsigned short* __restrict__ Qb,
                                              const unsigned short* __restrict__ Kb,
                                              const unsigned short* __restrict__ Vt,
                                              unsigned short* __restrict__ ctxb) {
    __shared__ unsigned short lK[2][64 * 64];
    __shared__ unsigned short lV[2][64 * 64];
    __shared__ unsigned short lP[8][16 * 64];

    const int t = threadIdx.x, w = t >> 6, l = t & 63;
    const int wv = w & 3;
    const int sel = w >> 2;
    const int h = blockIdx.x;
    const int qA = blockIdx.y;              // 0..31
    const int qB = 63 - qA;                 // 32..63
    const int qT = sel ? qB : qA;
    const int q0 = qT * 64 + wv * 16;
    const int g = l >> 4, ln = l & 15;

    bf16x8 aq[2];
    #pragma unroll
    for (int kk = 0; kk < 2; ++kk)
        aq[kk] = *(const bf16x8*)&Qb[(size_t)(q0 + ln) * LDQKV + h * 64 + kk * 32 + g * 8];

    f32x4 acc[4] = {};
    float rm = -INFINITY, rs = 0.0f;
    char* lpw = (char*)&lP[w][0];

    stage8(Kb, Vt, &lK[0][0], &lV[0][0], h, 0, w, l);
    asm volatile("s_waitcnt vmcnt(0)" ::: "memory");
    __syncthreads();

    int cur = 0;
    for (int kt = 0; kt <= qB; ++kt) {
        if (kt < qB)
            stage8(Kb, Vt, &lK[cur ^ 1][0], &lV[cur ^ 1][0], h, kt + 1, w, l);

        if (kt <= qT) {
            float p[16];
            __builtin_amdgcn_s_setprio(1);
            #pragma unroll
            for (int ct = 0; ct < 4; ++ct) {
                f32x4 z = {};
                #pragma unroll
                for (int kk = 0; kk < 2; ++kk) {
                    int row = ct * 16 + ln;
                    int off = (row * 128 + kk * 64 + g * 16) ^ ((row & 7) << 4);
                    bf16x8 ak = *(const bf16x8*)((const char*)&lK[cur][0] + off);
                    z = __builtin_amdgcn_mfma_f32_16x16x32_bf16(ak, aq[kk], z, 0, 0, 0);
                }
                #pragma unroll
                for (int r = 0; r < 4; ++r) p[ct * 4 + r] = z[r];
            }
            __builtin_amdgcn_s_setprio(0);

            if (kt == qT) {
                int qg = q0 + ln;
                #pragma unroll
                for (int ct = 0; ct < 4; ++ct)
                    #pragma unroll
                    for (int r = 0; r < 4; ++r)
                        if (kt * 64 + ct * 16 + g * 4 + r > qg) p[ct * 4 + r] = -INFINITY;
            }

            float pmax = fmaxf(p[0], p[1]);
            #pragma unroll
            for (int i = 2; i < 16; i += 2)
                pmax = fmaxf(fmaxf(pmax, p[i]), p[i + 1]);
            pmax = fmaxf(pmax, __shfl_xor(pmax, 16, 64));
            pmax = fmaxf(pmax, __shfl_xor(pmax, 32, 64));
            if (__any(pmax > rm + 8.0f)) {
                float mn = fmaxf(rm, pmax);
                float fac = __builtin_amdgcn_exp2f(rm - mn);
                rm = mn;
                rs *= fac;
                #pragma unroll
                for (int mb = 0; mb < 4; ++mb) {
                    f32x4 a = acc[mb];
                    #pragma unroll
                    for (int r = 0; r < 4; ++r) a[r] *= fac;
                    acc[mb] = a;
                }
            }
            float ps = 0.0f;
            #pragma unroll
            for (int i = 0; i < 16; ++i) {
                float e = __builtin_amdgcn_exp2f(p[i] - rm);
                p[i] = e;
                ps += e;
            }
            ps += __shfl_xor(ps, 16, 64);
            ps += __shfl_xor(ps, 32, 64);
            rs += ps;

            #pragma unroll
            for (int ct = 0; ct < 4; ++ct) {
                bf16x4 pv;
                pv[0] = (__bf16)p[ct * 4 + 0];
                pv[1] = (__bf16)p[ct * 4 + 1];
                pv[2] = (__bf16)p[ct * 4 + 2];
                pv[3] = (__bf16)p[ct * 4 + 3];
                int off = (ln * 128 + ct * 32 + g * 8) ^ ((ln & 7) << 4);
                *(bf16x4*)(lpw + off) = pv;
            }

            __builtin_amdgcn_s_setprio(1);
            #pragma unroll
            for (int mb = 0; mb < 4; ++mb) {
                #pragma unroll
                for (int kc = 0; kc < 2; ++kc) {
                    int vrow = mb * 16 + ln;
                    int voff = (vrow * 128 + kc * 64 + g * 16) ^ ((vrow & 7) << 4);
                    bf16x8 av = *(const bf16x8*)((const char*)&lV[cur][0] + voff);
                    int poff = (ln * 128 + kc * 64 + g * 16) ^ ((ln & 7) << 4);
                    bf16x8 bp = *(const bf16x8*)(lpw + poff);
                    acc[mb] = __builtin_amdgcn_mfma_f32_16x16x32_bf16(av, bp, acc[mb], 0, 0, 0);
                }
            }
            __builtin_amdgcn_s_setprio(0);
        }

        asm volatile("s_waitcnt vmcnt(0)" ::: "memory");
        __syncthreads();
        cur ^= 1;
    }

    float inv = 1.0f / rs;
    #pragma unroll
    for (int mb = 0; mb < 4; ++mb) {
        bf16x4 o;
        #pragma unroll
        for (int r = 0; r < 4; ++r) o[r] = (__bf16)(acc[mb][r] * inv);
        *(bf16x4*)&ctxb[(size_t)(q0 + ln) * D_MODEL + h * 64 + mb * 16 + g * 4] = o;
    }
}

// ---------------- host side ----------------
extern "C" void kernel_launch(void* const* d_in, const int* in_sizes, int n_in,
                              void* d_out, int out_size, void* d_ws, size_t ws_size,
                              hipStream_t stream) {
    const float* x  = (const float*)d_in[0];
    const float* Wq = (const float*)d_in[1];
    const float* Wk = (const float*)d_in[2];
    const float* Wv = (const float*)d_in[3];
    const float* Wo = (const float*)d_in[4];
    const int* tpos = (const int*)d_in[5];
    float* out = (float*)d_out;

    char* ws = (char*)d_ws;
    unsigned short* xb   = (unsigned short*)(ws + 0);            // 8 MB (dead after QKV gemm)
    unsigned short* Wb   = (unsigned short*)(ws + (8u << 20));   // 8 MB (Wq,Wk,Wv,Wo bf16)
    unsigned short* QKV  = (unsigned short*)(ws + (16u << 20));  // 24 MB [S][3072]
    unsigned short* ctxb = (unsigned short*)(ws + (40u << 20));  // 8 MB
    float* costab = (float*)(ws + (48u << 20));                  // 1 MB [4096][64]
    float* sintab = (float*)(ws + (49u << 20));                  // 1 MB
    unsigned short* Vtb  = xb;   // reuse: written by vtrans after QKV gemm

    // prep: x->bf16 | weights->bf16 | extended RoPE tables
    prep_k<<<9216, 256, 0, stream>>>(x, Wq, Wk, Wv, Wo, tpos, xb, Wb, costab, sintab);

    // fused QKV projection with RoPE/scale epilogue: 768 blocks = 3/CU
    gemm_qkv_k<<<dim3(24, 32), 256, 0, stream>>>(xb, Wb, QKV, costab, sintab);

    // V transpose: QKV cols 2048.. -> Vt [1024][S]
    vtrans_k<<<dim3(S_LEN / 64, D_MODEL / 64), 256, 0, stream>>>(QKV + 2048, Vtb);

    // paired causal attention: 32 balanced blocks per head
    attn_k<<<dim3(N_HEADS, 32), 512, 0, stream>>>(QKV, QKV + 1024, Vtb, ctxb);

    // out projection, 64x128 tiles: 512 blocks = 2/CU
    gemm_o_k<<<dim3(8, 64), 256, 0, stream>>>(ctxb, Wb + 3u * 1024 * 1024, out);
}